// Round 4
// baseline (111.616 us; speedup 1.0000x reference)
//
#include <hip/hip_runtime.h>
#include <hip/hip_bf16.h>

#define B_N  4096
#define K_D  1024
#define TILE 128
#define BK   64
#define KT   (K_D / BK)              // 16 K-tiles
#define NT   (B_N / TILE)            // 32 tile-rows
#define NBLK (NT * (NT + 1) / 2)     // 528 upper-triangular tiles (= 66*8, XCD-divisible)

typedef __bf16 bf16x8 __attribute__((ext_vector_type(8)));
typedef float  f32x4  __attribute__((ext_vector_type(4)));

// round-to-nearest-even float -> bf16 bits (inputs are finite normals; no NaN path needed)
__device__ __forceinline__ unsigned short f2bf(float x) {
    union { float f; unsigned int u; } v; v.f = x;
    unsigned int r = v.u + 0x7fffu + ((v.u >> 16) & 1u);
    return (unsigned short)(r >> 16);
}

// One block (256 threads) per row: compute L2 norm, write bf16 normalized row.
// Also zeroes rowsum[row] (and possum) so no separate memset node is needed.
__global__ void normalize_bf16(const float* __restrict__ f, unsigned short* __restrict__ fnb,
                               float* __restrict__ rowsum) {
    const int row = blockIdx.x;
    const int tid = threadIdx.x;
    float4 v = ((const float4*)(f + (size_t)row * K_D))[tid];
    float s = v.x * v.x + v.y * v.y + v.z * v.z + v.w * v.w;
#pragma unroll
    for (int m = 1; m < 64; m <<= 1) s += __shfl_xor(s, m, 64);
    __shared__ float wsum[4];
    if ((tid & 63) == 0) wsum[tid >> 6] = s;
    __syncthreads();
    float tot = wsum[0] + wsum[1] + wsum[2] + wsum[3];
    float scale = 1.0f / fmaxf(sqrtf(tot), 1e-12f);
    ushort4 o;
    o.x = f2bf(v.x * scale); o.y = f2bf(v.y * scale);
    o.z = f2bf(v.z * scale); o.w = f2bf(v.w * scale);
    ((ushort4*)(fnb + (size_t)row * K_D))[tid] = o;
    if (tid == 0) rowsum[row] = 0.0f;
    if (row == 0 && tid == 1) rowsum[B_N] = 0.0f;   // possum slot
}

// LDS tile layout: [row][8 slots of 16B], slot XOR-swizzled by (row&7) (T2; measured
// 0 bank conflicts in rounds 2-3). Stored via pre-swizzled GLOBAL source
// (global_load_lds writes linearly); read with the same XOR.
__device__ __forceinline__ const bf16x8* lds_frag(const unsigned short* base, int row, int ks) {
    return (const bf16x8*)((const char*)base + row * (BK * 2) + (((ks ^ row) & 7) << 4));
}

// Upper-triangular 128x128 tiles of sim = fn*fn^T (symmetric): 528 blocks, 2/CU
// resident (LDS 65 KB). Off-diagonal tile (bi<bj) computed once, credited twice:
// row sums -> rowsum[row-block], column sums (quad-reduce) -> rowsum[col-block],
// pospart*2. Diagonal tiles: Bg==Ag automatically (same pointer), single credit.
// 4 waves (2x2), per-wave 64x64 = 4x4 frags of 16x16x32 bf16 MFMA.
// K-loop: round-2-verified coarse schedule -- double-buffered LDS, counted vmcnt(8)
// (tile t+2's 8 loads stay in flight across tile t+1's compute; never drain to 0
// mid-loop), raw s_barrier, setprio around the MFMA cluster.
__global__ __launch_bounds__(256, 2)
void gemm_exp_reduce(const unsigned short* __restrict__ fnb,
                     const int* __restrict__ labels,
                     float* __restrict__ rowsum,
                     float* __restrict__ possum) {
    __shared__ __align__(16) unsigned short AsB[2][TILE * BK]; // 2 x 16 KB
    __shared__ __align__(16) unsigned short BsB[2][TILE * BK]; // 2 x 16 KB
    __shared__ int   rlab[TILE];
    __shared__ int   clab[TILE];
    __shared__ float posred[4];

    // XCD-bijective swizzle (T1): 528 = 66*8 -> 66 contiguous triangular indices/XCD
    // (consecutive t share bi -> A-panel L2 reuse within an XCD).
    const int t0 = (blockIdx.x & 7) * (NBLK / 8) + (blockIdx.x >> 3);
    int t  = t0;
    int bi = 0;
    while (t >= NT - bi) { t -= NT - bi; ++bi; }
    const int  bj   = bi + t;
    const bool diag = (bi == bj);

    const int row0 = bi * TILE, col0 = bj * TILE;
    const int tid  = threadIdx.x;
    const int lane = tid & 63, wave = tid >> 6;
    const int wr = wave >> 1, wc = wave & 1;          // 2x2 wave grid
    const int quad = lane >> 4, l15 = lane & 15;

    if (tid < TILE) rlab[tid] = labels[row0 + tid];
    else            clab[tid - TILE] = labels[col0 + tid - TILE];

    const unsigned short* Ag = fnb + (size_t)row0 * K_D;
    const unsigned short* Bg = fnb + (size_t)col0 * K_D;   // == Ag when diag

    f32x4 acc[4][4];
#pragma unroll
    for (int i = 0; i < 4; ++i)
#pragma unroll
        for (int j = 0; j < 4; ++j) {
            f32x4 z = {0.f, 0.f, 0.f, 0.f};
            acc[i][j] = z;
        }

    // Stage one K-tile (A rows row0..+127 and B rows col0..+127, cols k0..k0+63).
    // Chunk c = ld*256+tid -> LDS bytes [c*16,+16) (linear, lane-ordered, as
    // global_load_lds requires); global source column pre-swizzled: slot^(row&7).
    // 8 global_load_lds per thread per call.
    auto stage = [&](int buf, int k0) {
#pragma unroll
        for (int ld = 0; ld < 4; ++ld) {
            int c  = ld * 256 + tid;
            int r  = c >> 3;
            int gc = ((c ^ r) & 7) << 3;
            __builtin_amdgcn_global_load_lds(
                (const unsigned int*)(Ag + (size_t)r * K_D + k0 + gc),
                (unsigned int*)&AsB[buf][c * 8], 16, 0, 0);
        }
#pragma unroll
        for (int ld = 0; ld < 4; ++ld) {
            int c  = ld * 256 + tid;
            int r  = c >> 3;
            int gc = ((c ^ r) & 7) << 3;
            __builtin_amdgcn_global_load_lds(
                (const unsigned int*)(Bg + (size_t)r * K_D + k0 + gc),
                (unsigned int*)&BsB[buf][c * 8], 16, 0, 0);
        }
    };

    // Prologue: tiles 0 and 1 in flight (16 loads); wait tile 0 only (vmcnt(8)).
    stage(0, 0);
    stage(1, BK);
    asm volatile("s_waitcnt vmcnt(8)" ::: "memory");
    __builtin_amdgcn_sched_barrier(0);
    __builtin_amdgcn_s_barrier();
    __builtin_amdgcn_sched_barrier(0);

    for (int t2 = 0; t2 < KT; ++t2) {
        const unsigned short* A  = AsB[t2 & 1];
        const unsigned short* Bt = BsB[t2 & 1];

        bf16x8 af[4][2], bq[4][2];
#pragma unroll
        for (int fr = 0; fr < 4; ++fr)
#pragma unroll
            for (int kk = 0; kk < 2; ++kk)
                af[fr][kk] = *lds_frag(A, wr * 64 + fr * 16 + l15, kk * 4 + quad);
#pragma unroll
        for (int fc = 0; fc < 4; ++fc)
#pragma unroll
            for (int kk = 0; kk < 2; ++kk)
                bq[fc][kk] = *lds_frag(Bt, wc * 64 + fc * 16 + l15, kk * 4 + quad);

        __builtin_amdgcn_s_setprio(1);
#pragma unroll
        for (int fr = 0; fr < 4; ++fr)
#pragma unroll
            for (int fc = 0; fc < 4; ++fc)
#pragma unroll
                for (int kk = 0; kk < 2; ++kk)
                    acc[fr][fc] = __builtin_amdgcn_mfma_f32_16x16x32_bf16(
                        af[fr][kk], bq[fc][kk], acc[fr][fc], 0, 0, 0);
        __builtin_amdgcn_s_setprio(0);

        __builtin_amdgcn_sched_barrier(0);
        __builtin_amdgcn_s_barrier();      // all waves done READING buf[t2&1]
        __builtin_amdgcn_sched_barrier(0);
        if (t2 + 2 < KT) {
            stage(t2 & 1, (t2 + 2) * BK);  // overwrite just-consumed buffer
            // outstanding <= 8 (tile t2+1) + 8 (tile t2+2); wait t2+1 only.
            asm volatile("s_waitcnt vmcnt(8)" ::: "memory");
        } else if (t2 + 1 < KT) {
            asm volatile("s_waitcnt vmcnt(0)" ::: "memory");  // drain last tile
        }
        if (t2 + 1 < KT) {
            __builtin_amdgcn_sched_barrier(0);
            __builtin_amdgcn_s_barrier();  // buf[(t2+1)&1] fully arrived (all waves)
            __builtin_amdgcn_sched_barrier(0);
        }
    }

    // Epilogue. C/D layout (m89/m91-verified): col = lane&15, row = quad*4 + reg.
    float pospart = 0.0f;
    float cs[4] = {0.f, 0.f, 0.f, 0.f};   // per-fc column sums (lane's column, over fr,r)
#pragma unroll
    for (int fr = 0; fr < 4; ++fr) {
        float rp[4] = {0.f, 0.f, 0.f, 0.f};
#pragma unroll
        for (int fc = 0; fc < 4; ++fc) {
            int c    = wc * 64 + fc * 16 + l15;
            int gcol = col0 + c;
            int cl   = clab[c];
#pragma unroll
            for (int r = 0; r < 4; ++r) {
                int rr   = wr * 64 + fr * 16 + quad * 4 + r;
                int grow = row0 + rr;
                float e  = (grow == gcol) ? 0.0f : __expf(acc[fr][fc][r] * 10.0f);
                rp[r] += e;
                cs[fc] += e;
                pospart += (rlab[rr] == cl) ? e : 0.0f;
            }
        }
        // row sums: reduce across the 16 columns (lanes sharing a quad)
#pragma unroll
        for (int r = 0; r < 4; ++r) {
            float v = rp[r];
            v += __shfl_xor(v, 1, 64);
            v += __shfl_xor(v, 2, 64);
            v += __shfl_xor(v, 4, 64);
            v += __shfl_xor(v, 8, 64);
            if (l15 == 0)
                atomicAdd(&rowsum[row0 + wr * 64 + fr * 16 + quad * 4 + r], v);
        }
    }
    if (!diag) {
        // column sums: reduce across the 4 quads (rows of this wave's 64-row band)
#pragma unroll
        for (int fc = 0; fc < 4; ++fc) {
            float v = cs[fc];
            v += __shfl_xor(v, 16, 64);
            v += __shfl_xor(v, 32, 64);
            if (quad == 0)
                atomicAdd(&rowsum[col0 + wc * 64 + fc * 16 + l15], v);
        }
        pospart *= 2.0f;   // mirror tile (bj,bi) contributes identically
    }
#pragma unroll
    for (int m = 1; m < 64; m <<= 1) pospart += __shfl_xor(pospart, m, 64);
    if (lane == 0) posred[wave] = pospart;
    __syncthreads();
    if (tid == 0)
        atomicAdd(possum, posred[0] + posred[1] + posred[2] + posred[3]);
}

__global__ void finalize(const float* __restrict__ rowsum,
                         const float* __restrict__ possum,
                         float* __restrict__ out) {
    const int tid = threadIdx.x;
    float s = 0.f;
    for (int i = tid; i < B_N; i += 256) s += logf(rowsum[i]);
#pragma unroll
    for (int m = 1; m < 64; m <<= 1) s += __shfl_xor(s, m, 64);
    __shared__ float w[4];
    if ((tid & 63) == 0) w[tid >> 6] = s;
    __syncthreads();
    if (tid == 0) {
        float tot = w[0] + w[1] + w[2] + w[3];
        // loss = mean_i log(rowsum_i)  -  log(possum)
        out[0] = tot / (float)B_N - logf(possum[0]);
    }
}

extern "C" void kernel_launch(void* const* d_in, const int* in_sizes, int n_in,
                              void* d_out, int out_size, void* d_ws, size_t ws_size,
                              hipStream_t stream) {
    const float* features = (const float*)d_in[0];
    const int*   targets  = (const int*)d_in[1];
    float*       out      = (float*)d_out;

    // workspace layout: [bf16 fn: 8 MB][rowsum: 4096 f32][possum: 1 f32]
    unsigned short* fnb    = (unsigned short*)d_ws;
    float*          rowsum = (float*)((char*)d_ws + (size_t)B_N * K_D * sizeof(unsigned short));
    float*          possum = rowsum + B_N;

    normalize_bf16<<<B_N, 256, 0, stream>>>(features, fnb, rowsum);
    gemm_exp_reduce<<<NBLK, 256, 0, stream>>>(fnb, targets, rowsum, possum);
    finalize<<<1, 256, 0, stream>>>(rowsum, possum, out);
}